// Round 16
// baseline (333.900 us; speedup 1.0000x reference)
//
#include <hip/hip_runtime.h>

#define N_NODES 32000
typedef unsigned short u16;
typedef unsigned int u32;
typedef unsigned char u8;
typedef __attribute__((ext_vector_type(8))) short bf16x8;
typedef __attribute__((ext_vector_type(4))) float f32x4;
typedef __attribute__((ext_vector_type(2))) float f32x2;

__device__ __forceinline__ float leakyf(float v) { return v >= 0.f ? v : 0.1f * v; }
__device__ __forceinline__ u16 f2bf(float f) {
    u32 u = __float_as_uint(f);
    return (u16)((u + 0x7FFFu + ((u >> 16) & 1u)) >> 16);
}
__device__ __forceinline__ float bf_lo(u32 u) { return __uint_as_float(u << 16); }
__device__ __forceinline__ float bf_hi(u32 u) { return __uint_as_float(u & 0xFFFF0000u); }
__device__ __forceinline__ u32 pack2(float a, float b) { return (u32)f2bf(a) | ((u32)f2bf(b) << 16); }

__device__ __forceinline__ void dec4(float* acc, u32 w) {
    f32x2 lo = __builtin_amdgcn_cvt_pk_f32_fp8(w, false);
    f32x2 hi = __builtin_amdgcn_cvt_pk_f32_fp8(w, true);
    acc[0] += lo[0]; acc[1] += lo[1]; acc[2] += hi[0]; acc[3] += hi[1];
}
__device__ __forceinline__ void dec16(float* acc, uint4 v) {
    dec4(acc + 0, v.x); dec4(acc + 4, v.y); dec4(acc + 8, v.z); dec4(acc + 12, v.w);
}
__device__ __forceinline__ u8 f2fp8(float v) {
    return (u8)__builtin_amdgcn_cvt_pk_fp8_f32(v, v, 0, false);
}

__device__ __forceinline__ void gload16(const u16* g, u16* l) {
    __builtin_amdgcn_global_load_lds((const __attribute__((address_space(1))) void*)g,
                                     (__attribute__((address_space(3))) void*)l, 16, 0, 0);
}

// ---------------- fused prep: edge-count | x->fp8 | weights->bf16 ----------------
__global__ __launch_bounds__(256) void k_prep(const int* __restrict__ dst, int* __restrict__ cnt, int E,
                                              const float* __restrict__ x, u32* __restrict__ x8,
                                              const float* __restrict__ W1, const float* __restrict__ W2,
                                              const float* __restrict__ W3, u16* __restrict__ o1,
                                              u16* __restrict__ o2, u16* __restrict__ o3)
{
    const int b = blockIdx.x, t = threadIdx.x;
    if (b < 2000) {
        int e = b * 256 + t;
        if (e < E) atomicAdd(&cnt[dst[e]], 1);
    } else if (b < 10000) {
        int i = (b - 2000) * 256 + t;
        float4 v = ((const float4*)x)[i];
        int p = __builtin_amdgcn_cvt_pk_fp8_f32(v.x, v.y, 0, false);
        p = __builtin_amdgcn_cvt_pk_fp8_f32(v.z, v.w, p, true);
        x8[i] = (u32)p;
    } else {
        int bb = b - 10000;
        const float* in; u16* out; int i;
        if (bb < 128)      { in = W1; out = o1; i = bb * 256 + t; }
        else if (bb < 384) { in = W2; out = o2; i = (bb - 128) * 256 + t; }
        else               { in = W3; out = o3; i = (bb - 384) * 256 + t; }
        float4 v = ((const float4*)in)[i];
        ushort4 o;
        o.x = f2bf(v.x); o.y = f2bf(v.y); o.z = f2bf(v.z); o.w = f2bf(v.w);
        ((ushort4*)out)[i] = o;
    }
}

// ---------------- CSR scan ----------------
__global__ __launch_bounds__(256) void k_scan_blk(const int* __restrict__ cnt, int* __restrict__ rp,
                                                  int* __restrict__ bsum)
{
    __shared__ int sh[256];
    const int b = blockIdx.x, t = threadIdx.x;
    int v = cnt[b * 256 + t];
    sh[t] = v;
    __syncthreads();
    for (int off = 1; off < 256; off <<= 1) {
        int u = (t >= off) ? sh[t - off] : 0;
        __syncthreads();
        sh[t] += u;
        __syncthreads();
    }
    rp[b * 256 + t] = sh[t] - v;
    if (t == 255) bsum[b] = sh[255];
}

__global__ __launch_bounds__(256) void k_scan_add(int* __restrict__ rp, const int* __restrict__ bsum,
                                                  int nb, int n, int E)
{
    __shared__ int sh[256];
    const int b = blockIdx.x, t = threadIdx.x;
    int v = (t < b && t < nb) ? bsum[t] : 0;
    sh[t] = v;
    __syncthreads();
    for (int off = 128; off > 0; off >>= 1) {
        if (t < off) sh[t] += sh[t + off];
        __syncthreads();
    }
    int i = b * 256 + t;
    rp[i] += sh[0];
    if (i == 0) rp[n] = E;
}

__global__ __launch_bounds__(256) void k_place(const int* __restrict__ src, const int* __restrict__ dst,
                                               const int* __restrict__ rp, int* __restrict__ cur,
                                               int* __restrict__ cs, int E)
{
    int e = blockIdx.x * 256 + threadIdx.x;
    if (e < E) {
        int d = dst[e];
        int p = rp[d] + atomicAdd(&cur[d], 1);
        cs[p] = src[e];
    }
}

// ---------------- bf16 MFMA GEMM, dbuf + counted vmcnt; optional fused column stats ----------------
template <bool RELU, bool DEGB, bool F8OUT, bool STATS>
__global__ __launch_bounds__(256) void k_gemm_mfma(const u16* __restrict__ A, const u16* __restrict__ W,
                                                   const float* __restrict__ bias, const int* __restrict__ rp,
                                                   void* __restrict__ Cv, float* __restrict__ partial,
                                                   int K, int OD)
{
    __shared__ u16 As[2][128 * 32];
    __shared__ u16 Bs[2][128 * 32];
    const int t = threadIdx.x;
    const int lane = t & 63;
    const int w = t >> 6;
    const int wr = w >> 1, wc = w & 1;
    const int bm = blockIdx.x * 128;
    const int bn = blockIdx.y * 128;

    const int c0 = w * 64 + lane;
    const int r0 = c0 >> 2, kc0 = (c0 & 3) * 8;
    const int c1 = c0 + 256;
    const int r1 = c1 >> 2, kc1 = (c1 & 3) * 8;
    const u16* gA0 = A + (size_t)(bm + r0) * K + kc0;
    const u16* gA1 = A + (size_t)(bm + r1) * K + kc1;
    const u16* gB0 = W + (size_t)(bn + r0) * K + kc0;
    const u16* gB1 = W + (size_t)(bn + r1) * K + kc1;

    f32x4 acc[4][4];
#pragma unroll
    for (int i = 0; i < 4; ++i)
#pragma unroll
        for (int j = 0; j < 4; ++j)
            acc[i][j] = (f32x4){0.f, 0.f, 0.f, 0.f};

    const int fr = lane & 15;
    const int ko = (lane >> 4) * 8;

    auto STAGE = [&](int b, int k0) {
        gload16(gA0 + k0, &As[b][0] + w * 512);
        gload16(gA1 + k0, &As[b][0] + 2048 + w * 512);
        gload16(gB0 + k0, &Bs[b][0] + w * 512);
        gload16(gB1 + k0, &Bs[b][0] + 2048 + w * 512);
    };

    STAGE(0, 0);

    int cur = 0;
    for (int k0 = 0; k0 < K; k0 += 32) {
        if (k0 + 32 < K) {
            STAGE(cur ^ 1, k0 + 32);
            asm volatile("s_waitcnt vmcnt(4)" ::: "memory");
        } else {
            asm volatile("s_waitcnt vmcnt(0)" ::: "memory");
        }
        __syncthreads();
        bf16x8 af[4], bfv[4];
#pragma unroll
        for (int i = 0; i < 4; ++i)
            af[i] = *(const bf16x8*)&As[cur][(wr * 64 + i * 16 + fr) * 32 + ko];
#pragma unroll
        for (int j = 0; j < 4; ++j)
            bfv[j] = *(const bf16x8*)&Bs[cur][(wc * 64 + j * 16 + fr) * 32 + ko];
#pragma unroll
        for (int i = 0; i < 4; ++i)
#pragma unroll
            for (int j = 0; j < 4; ++j)
                acc[i][j] = __builtin_amdgcn_mfma_f32_16x16x32_bf16(af[i], bfv[j], acc[i][j], 0, 0, 0);
        __syncthreads();
        cur ^= 1;
    }

    u16* C16 = (u16*)Cv;
    u8*  C8  = (u8*)Cv;
    const int qr = (lane >> 4) * 4;
    float bcol[4];
#pragma unroll
    for (int j = 0; j < 4; ++j) bcol[j] = bias[bn + wc * 64 + j * 16 + fr];
    float s4[4] = {}, q4[4] = {};
#pragma unroll
    for (int i = 0; i < 4; ++i) {
#pragma unroll
        for (int r = 0; r < 4; ++r) {
            int row = bm + wr * 64 + i * 16 + qr + r;
            float bm_ = 1.f;
            if (DEGB) bm_ = (float)(rp[row + 1] - rp[row]) + 1.f;
#pragma unroll
            for (int j = 0; j < 4; ++j) {
                int col = bn + wc * 64 + j * 16 + fr;
                float o = acc[i][j][r] + bm_ * bcol[j];
                if (RELU) o = fmaxf(o, 0.f);
                if (STATS) { s4[j] += o; q4[j] = fmaf(o, o, q4[j]); }
                if (F8OUT) C8[(size_t)row * OD + col] = f2fp8(o);
                else       C16[(size_t)row * OD + col] = f2bf(o);
            }
        }
    }

    if (STATS) {
#pragma unroll
        for (int j = 0; j < 4; ++j) {
            s4[j] += __shfl_xor(s4[j], 16); s4[j] += __shfl_xor(s4[j], 32);
            q4[j] += __shfl_xor(q4[j], 16); q4[j] += __shfl_xor(q4[j], 32);
        }
        __syncthreads();
        float* sred = (float*)&As[0][0];
        if ((lane >> 4) == 0) {
#pragma unroll
            for (int j = 0; j < 4; ++j) {
                sred[((w * 4 + j) * 16 + fr) * 2 + 0] = s4[j];
                sred[((w * 4 + j) * 16 + fr) * 2 + 1] = q4[j];
            }
        }
        __syncthreads();
        if (wr == 0 && (lane >> 4) == 0) {
#pragma unroll
            for (int j = 0; j < 4; ++j) {
                int i0 = ((w * 4 + j) * 16 + fr) * 2;
                int i1 = (((w + 2) * 4 + j) * 16 + fr) * 2;
                float ss = sred[i0] + sred[i1];
                float qq = sred[i0 + 1] + sred[i1 + 1];
                int col = bn + wc * 64 + j * 16 + fr;
                partial[(size_t)blockIdx.x * 1024 + col]       = ss;
                partial[(size_t)blockIdx.x * 1024 + 512 + col] = qq;
            }
        }
    }
}

// ---------------- fp8 gather+self, D=256, plain (layer 1; no relu, no stats) ----------------
template <bool RELU>
__global__ __launch_bounds__(256) void k_agg256_f8(const u8* __restrict__ h8, const int* __restrict__ rp,
                                                   const int* __restrict__ cs, u16* __restrict__ out)
{
    const int lane = threadIdx.x & 63;
    const int n = blockIdx.x * 4 + (threadIdx.x >> 6);
    const int g = lane >> 4;
    const int c = lane & 15;
    const uint4* hb = (const uint4*)h8 + c;

    float acc[16];
#pragma unroll
    for (int i = 0; i < 16; ++i) acc[i] = 0.f;
    if (g == 0) dec16(acc, hb[(size_t)n * 16]);

    const int beg = rp[n], end = rp[n + 1];
    int e = beg;
    for (; e + 16 <= end; e += 16) {
        uint4 v0 = hb[(size_t)cs[e + g] * 16];
        uint4 v1 = hb[(size_t)cs[e + 4 + g] * 16];
        uint4 v2 = hb[(size_t)cs[e + 8 + g] * 16];
        uint4 v3 = hb[(size_t)cs[e + 12 + g] * 16];
        dec16(acc, v0); dec16(acc, v1); dec16(acc, v2); dec16(acc, v3);
    }
    for (; e + 4 <= end; e += 4) {
        uint4 v = hb[(size_t)cs[e + g] * 16];
        dec16(acc, v);
    }
    if (e + g < end) {
        uint4 v = hb[(size_t)cs[e + g] * 16];
        dec16(acc, v);
    }
#pragma unroll
    for (int i = 0; i < 16; ++i) acc[i] += __shfl_xor(acc[i], 16);
#pragma unroll
    for (int i = 0; i < 16; ++i) acc[i] += __shfl_xor(acc[i], 32);
    if (g == 0) {
        if (RELU) {
#pragma unroll
            for (int i = 0; i < 16; ++i) acc[i] = fmaxf(acc[i], 0.f);
        }
        uint4 o0, o1;
        o0.x = pack2(acc[0], acc[1]);  o0.y = pack2(acc[2], acc[3]);
        o0.z = pack2(acc[4], acc[5]);  o0.w = pack2(acc[6], acc[7]);
        o1.x = pack2(acc[8], acc[9]);  o1.y = pack2(acc[10], acc[11]);
        o1.z = pack2(acc[12], acc[13]); o1.w = pack2(acc[14], acc[15]);
        uint4* op = (uint4*)((u32*)out + (size_t)n * 128 + c * 8);
        op[0] = o0; op[1] = o1;
    }
}

// ---------------- fp8 gather+self+relu, D=512, FUSED column stats (layer 2) ----------------
// 2000 blocks x 16 nodes (4 waves x 4 nodes). Per-wave LDS stats [i*32+c] (bank-conflict-free);
// block writes partial[blk][1024] = sum[512] | sq[512] (same format bn_red1 expects).
__global__ __launch_bounds__(256) void k_agg512_f8s(const u8* __restrict__ h8, const int* __restrict__ rp,
                                                    const int* __restrict__ cs, u16* __restrict__ out,
                                                    float* __restrict__ partial)
{
    __shared__ float sw[4][1024];
    const int t = threadIdx.x;
    const int w = t >> 6;
    const int lane = t & 63;
    const int g = lane >> 5;
    const int c = lane & 31;
    for (int i = lane; i < 1024; i += 64) sw[w][i] = 0.f;
    const uint4* hb = (const uint4*)h8 + c;

#pragma unroll 1
    for (int nn = 0; nn < 4; ++nn) {
        const int n = blockIdx.x * 16 + w * 4 + nn;
        float acc[16];
#pragma unroll
        for (int i = 0; i < 16; ++i) acc[i] = 0.f;
        if (g == 0) dec16(acc, hb[(size_t)n * 32]);
        const int beg = rp[n], end = rp[n + 1];
        int e = beg;
        for (; e + 8 <= end; e += 8) {
            uint4 v0 = hb[(size_t)cs[e + g] * 32];
            uint4 v1 = hb[(size_t)cs[e + 2 + g] * 32];
            uint4 v2 = hb[(size_t)cs[e + 4 + g] * 32];
            uint4 v3 = hb[(size_t)cs[e + 6 + g] * 32];
            dec16(acc, v0); dec16(acc, v1); dec16(acc, v2); dec16(acc, v3);
        }
        for (; e + 2 <= end; e += 2) {
            uint4 v = hb[(size_t)cs[e + g] * 32];
            dec16(acc, v);
        }
        if (e + g < end) {
            uint4 v = hb[(size_t)cs[e + g] * 32];
            dec16(acc, v);
        }
#pragma unroll
        for (int i = 0; i < 16; ++i) acc[i] += __shfl_xor(acc[i], 32);
        if (g == 0) {
#pragma unroll
            for (int i = 0; i < 16; ++i) {
                float a = fmaxf(acc[i], 0.f);
                acc[i] = a;
                sw[w][i * 32 + c] += a;
                sw[w][512 + i * 32 + c] = fmaf(a, a, sw[w][512 + i * 32 + c]);
            }
            uint4 o0, o1;
            o0.x = pack2(acc[0], acc[1]);  o0.y = pack2(acc[2], acc[3]);
            o0.z = pack2(acc[4], acc[5]);  o0.w = pack2(acc[6], acc[7]);
            o1.x = pack2(acc[8], acc[9]);  o1.y = pack2(acc[10], acc[11]);
            o1.z = pack2(acc[12], acc[13]); o1.w = pack2(acc[14], acc[15]);
            uint4* op = (uint4*)((u32*)out + (size_t)n * 256 + c * 8);
            op[0] = o0; op[1] = o1;
        }
    }
    __syncthreads();
    float* pb = partial + (size_t)blockIdx.x * 1024;
#pragma unroll
    for (int r = 0; r < 4; ++r) {
        int o = t + r * 256;
        int base = (o < 512) ? 0 : 512;
        int col = o - base;
        int addr = base + (col & 15) * 32 + (col >> 4);
        pb[o] = sw[0][addr] + sw[1][addr] + sw[2][addr] + sw[3][addr];
    }
}

// ---------------- fp8 gather+self+relu, D=256, FUSED column stats (layer 3) ----------------
// 2000 blocks x 16 nodes; partial[blk][512] = sum[256] | sq[256].
__global__ __launch_bounds__(256) void k_agg256_f8s(const u8* __restrict__ h8, const int* __restrict__ rp,
                                                    const int* __restrict__ cs, u16* __restrict__ out,
                                                    float* __restrict__ partial)
{
    __shared__ float sw[4][512];
    const int t = threadIdx.x;
    const int w = t >> 6;
    const int lane = t & 63;
    const int g = lane >> 4;
    const int c = lane & 15;
    for (int i = lane; i < 512; i += 64) sw[w][i] = 0.f;
    const uint4* hb = (const uint4*)h8 + c;

#pragma unroll 1
    for (int nn = 0; nn < 4; ++nn) {
        const int n = blockIdx.x * 16 + w * 4 + nn;
        float acc[16];
#pragma unroll
        for (int i = 0; i < 16; ++i) acc[i] = 0.f;
        if (g == 0) dec16(acc, hb[(size_t)n * 16]);
        const int beg = rp[n], end = rp[n + 1];
        int e = beg;
        for (; e + 16 <= end; e += 16) {
            uint4 v0 = hb[(size_t)cs[e + g] * 16];
            uint4 v1 = hb[(size_t)cs[e + 4 + g] * 16];
            uint4 v2 = hb[(size_t)cs[e + 8 + g] * 16];
            uint4 v3 = hb[(size_t)cs[e + 12 + g] * 16];
            dec16(acc, v0); dec16(acc, v1); dec16(acc, v2); dec16(acc, v3);
        }
        for (; e + 4 <= end; e += 4) {
            uint4 v = hb[(size_t)cs[e + g] * 16];
            dec16(acc, v);
        }
        if (e + g < end) {
            uint4 v = hb[(size_t)cs[e + g] * 16];
            dec16(acc, v);
        }
#pragma unroll
        for (int i = 0; i < 16; ++i) acc[i] += __shfl_xor(acc[i], 16);
#pragma unroll
        for (int i = 0; i < 16; ++i) acc[i] += __shfl_xor(acc[i], 32);
        if (g == 0) {
#pragma unroll
            for (int i = 0; i < 16; ++i) {
                float a = fmaxf(acc[i], 0.f);
                acc[i] = a;
                sw[w][i * 16 + c] += a;
                sw[w][256 + i * 16 + c] = fmaf(a, a, sw[w][256 + i * 16 + c]);
            }
            uint4 o0, o1;
            o0.x = pack2(acc[0], acc[1]);  o0.y = pack2(acc[2], acc[3]);
            o0.z = pack2(acc[4], acc[5]);  o0.w = pack2(acc[6], acc[7]);
            o1.x = pack2(acc[8], acc[9]);  o1.y = pack2(acc[10], acc[11]);
            o1.z = pack2(acc[12], acc[13]); o1.w = pack2(acc[14], acc[15]);
            uint4* op = (uint4*)((u32*)out + (size_t)n * 128 + c * 8);
            op[0] = o0; op[1] = o1;
        }
    }
    __syncthreads();
    float* pb = partial + (size_t)blockIdx.x * 512;
#pragma unroll
    for (int r = 0; r < 2; ++r) {
        int o = t + r * 256;
        int base = (o < 256) ? 0 : 256;
        int col = o - base;
        int addr = base + (col & 15) * 16 + (col >> 4);
        pb[o] = sw[0][addr] + sw[1][addr] + sw[2][addr] + sw[3][addr];
    }
}

// ---------------- BN stats reduce, level 1: P rows -> SEG rows (no atomics) ----------------
template <int D, int P, int SEG>
__global__ __launch_bounds__(256) void k_bn_red1(const float* __restrict__ partial, float* __restrict__ part2)
{
    const int g = blockIdx.x * 256 + threadIdx.x;
    const int col = g & (2 * D - 1);
    const int seg = g / (2 * D);
    constexpr int CHUNK = P / SEG;
    const float* p = partial + (size_t)seg * CHUNK * (2 * D) + col;
    float acc = 0.f;
#pragma unroll
    for (int i = 0; i < CHUNK; ++i) acc += p[(size_t)i * (2 * D)];
    part2[(size_t)seg * (2 * D) + col] = acc;
}

// ---------------- BN stats reduce, level 2: SEG rows -> sums (direct store) ----------------
template <int D, int SEG>
__global__ __launch_bounds__(256) void k_bn_red2(const float* __restrict__ part2, float* __restrict__ sums)
{
    const int col = blockIdx.x * 256 + threadIdx.x;
    float acc = 0.f;
#pragma unroll
    for (int i = 0; i < SEG; ++i) acc += part2[(size_t)i * (2 * D) + col];
    sums[col] = acc;
}

// ---------------- BN apply with inline finalize ----------------
template <int D>
__global__ __launch_bounds__(256) void k_bn_apply(u16* __restrict__ h, const float* __restrict__ sums,
                                                  const float* __restrict__ gam, const float* __restrict__ bet)
{
    int i = blockIdx.x * 256 + threadIdx.x;
    int c = (i * 8) & (D - 1);
    const float invN = 1.f / (float)N_NODES;
    float sc[8], sh[8];
#pragma unroll
    for (int k = 0; k < 8; ++k) {
        float mu  = sums[c + k] * invN;
        float var = sums[D + c + k] * invN - mu * mu;
        float rs  = rsqrtf(var + 1e-5f);
        sc[k] = gam[c + k] * rs;
        sh[k] = bet[c + k] - mu * sc[k];
    }
    uint4 v = ((uint4*)h)[i];
    u32 vv[4] = {v.x, v.y, v.z, v.w};
    u32 r[4];
#pragma unroll
    for (int k = 0; k < 4; ++k) {
        float a = leakyf(fmaf(bf_lo(vv[k]), sc[2 * k], sh[2 * k]));
        float b = leakyf(fmaf(bf_hi(vv[k]), sc[2 * k + 1], sh[2 * k + 1]));
        r[k] = pack2(a, b);
    }
    ((uint4*)h)[i] = make_uint4(r[0], r[1], r[2], r[3]);
}

// ---------------- pool: BN3+leaky fused, NO atomics ----------------
__global__ __launch_bounds__(256) void k_pool_bn(const u16* __restrict__ h, const float* __restrict__ sums,
                                                 const float* __restrict__ gam, const float* __restrict__ bet,
                                                 float* __restrict__ ppool)
{
    const int t = threadIdx.x;
    const int s = t & 31;
    const int j = t >> 5;
    const int r0 = blockIdx.x * 16;
    const float invN = 1.f / (float)N_NODES;
    float sc[8], sh[8];
#pragma unroll
    for (int k = 0; k < 8; ++k) {
        int c = 8 * s + k;
        float mu  = sums[c] * invN;
        float var = sums[256 + c] * invN - mu * mu;
        float rs  = rsqrtf(var + 1e-5f);
        sc[k] = gam[c] * rs;
        sh[k] = bet[c] - mu * sc[k];
    }
    float a[8] = {};
#pragma unroll
    for (int rr = 0; rr < 2; ++rr) {
        int r = r0 + j + rr * 8;
        uint4 v = *((const uint4*)(h + (size_t)r * 256) + s);
        u32 wv[4] = {v.x, v.y, v.z, v.w};
#pragma unroll
        for (int k = 0; k < 4; ++k) {
            a[2 * k]     += leakyf(fmaf(bf_lo(wv[k]), sc[2 * k], sh[2 * k]));
            a[2 * k + 1] += leakyf(fmaf(bf_hi(wv[k]), sc[2 * k + 1], sh[2 * k + 1]));
        }
    }
    __shared__ float red[8][256];
#pragma unroll
    for (int i = 0; i < 8; ++i) red[i][t] = a[i];
    __syncthreads();
    if (j == 0) {
#pragma unroll
        for (int k = 1; k < 8; ++k) {
            int o = k * 32 + s;
#pragma unroll
            for (int i = 0; i < 8; ++i) a[i] += red[i][o];
        }
        float4* pb = (float4*)(ppool + (size_t)blockIdx.x * 256 + 8 * s);
        pb[0] = make_float4(a[0], a[1], a[2], a[3]);
        pb[1] = make_float4(a[4], a[5], a[6], a[7]);
    }
}

// ---------------- head: one block per graph ----------------
__global__ __launch_bounds__(256) void k_head(const float* __restrict__ ppool, const float* __restrict__ Wp,
                                              const float* __restrict__ bp, float* __restrict__ out)
{
    __shared__ float r0s[256], r1s[256];
    const int b = blockIdx.x, t = threadIdx.x;
    const float* p = ppool + (size_t)b * 125 * 256 + t;
    float g = 0.f;
#pragma unroll 5
    for (int i = 0; i < 125; ++i) g += p[(size_t)i * 256];
    g *= (1.f / 2000.f);
    r0s[t] = g * Wp[t];
    r1s[t] = g * Wp[256 + t];
    __syncthreads();
    for (int off = 128; off > 0; off >>= 1) {
        if (t < off) { r0s[t] += r0s[t + off]; r1s[t] += r1s[t + off]; }
        __syncthreads();
    }
    if (t == 0) {
        float o0 = r0s[0] + bp[0];
        float o1 = r1s[0] + bp[1];
        out[b * 2]     = o0;
        out[b * 2 + 1] = o1;
        out[32 + b]    = (o1 > o0) ? 1.f : 0.f;
    }
}

extern "C" void kernel_launch(void* const* d_in, const int* in_sizes, int n_in,
                              void* d_out, int out_size, void* d_ws, size_t ws_size,
                              hipStream_t stream)
{
    const float* x   = (const float*)d_in[0];
    const int*   ei  = (const int*)d_in[1];
    const float* W1  = (const float*)d_in[2];
    const float* b1  = (const float*)d_in[3];
    const float* W2  = (const float*)d_in[4];
    const float* b2  = (const float*)d_in[5];
    const float* W3  = (const float*)d_in[6];
    const float* b3  = (const float*)d_in[7];
    const float* g1  = (const float*)d_in[8];
    const float* be1 = (const float*)d_in[9];
    const float* g2  = (const float*)d_in[10];
    const float* be2 = (const float*)d_in[11];
    const float* g3  = (const float*)d_in[12];
    const float* be3 = (const float*)d_in[13];
    const float* Wp  = (const float*)d_in[14];
    const float* bp  = (const float*)d_in[15];
    float* out = (float*)d_out;

    const int E = in_sizes[1] / 2;
    const int* src = ei;
    const int* dst = ei + E;

    char* ws = (char*)d_ws;
    size_t off = 0;
    auto alloc = [&](size_t bytes) -> void* {
        void* p = ws + off;
        off = (off + bytes + 255) & ~(size_t)255;
        return p;
    };
    u16*   bufA = (u16*)alloc((size_t)N_NODES * 512 * 2);
    u16*   bufB = (u16*)alloc((size_t)N_NODES * 512 * 2);
    u8*    buf8 = (u8*)alloc((size_t)N_NODES * 512);
    u8*    x8   = (u8*)alloc((size_t)N_NODES * 256);
    u16*   w1b  = (u16*)alloc(512 * 256 * 2);
    u16*   w2b  = (u16*)alloc(512 * 512 * 2);
    u16*   w3b  = (u16*)alloc(256 * 512 * 2);
    int*   cs   = (int*)alloc((size_t)E * 4);
    int*   rp   = (int*)alloc((size_t)(N_NODES + 1) * 4);
    int*   cnt  = (int*)alloc((size_t)N_NODES * 4 * 2);
    int*   cur  = cnt + N_NODES;
    const size_t zbytes = (size_t)N_NODES * 8;
    int*   bsum = (int*)alloc(256 * 4);
    float* part = (float*)alloc((size_t)2000 * 1024 * 4);
    float* part2 = (float*)alloc((size_t)100 * 1024 * 4);
    float* sums1 = (float*)alloc(1024 * 4);
    float* sums2 = (float*)alloc(1024 * 4);
    float* sums3 = (float*)alloc(1024 * 4);
    float* ppool = (float*)alloc((size_t)2000 * 256 * 4);

    hipMemsetAsync(cnt, 0, zbytes, stream);

    const int eb = (E + 255) / 256;          // 2000
    const int nb = N_NODES / 256;            // 125

    k_prep<<<eb + 8000 + 512, 256, 0, stream>>>(dst, cnt, E, x, (u32*)x8, W1, W2, W3, w1b, w2b, w3b);
    k_scan_blk<<<nb, 256, 0, stream>>>(cnt, rp, bsum);
    k_scan_add<<<nb, 256, 0, stream>>>(rp, bsum, nb, N_NODES, E);
    k_place<<<eb, 256, 0, stream>>>(src, dst, rp, cur, cs, E);

    // ---- layer 1: stats fused in GEMM epilogue ----
    k_agg256_f8<false><<<N_NODES / 4, 256, 0, stream>>>(x8, rp, cs, bufA);
    k_gemm_mfma<true, true, false, true><<<dim3(250, 4), 256, 0, stream>>>(bufA, w1b, b1, rp, bufB, part, 256, 512);
    k_bn_red1<512, 250, 25><<<100, 256, 0, stream>>>(part, part2);
    k_bn_red2<512, 25><<<4, 256, 0, stream>>>(part2, sums1);
    k_bn_apply<512><<<N_NODES * 512 / 8 / 256, 256, 0, stream>>>(bufB, sums1, g1, be1);

    // ---- layer 2: GEMM -> agg+stats fused -> reduce -> apply ----
    k_gemm_mfma<false, false, true, false><<<dim3(250, 4), 256, 0, stream>>>(bufB, w2b, b2, rp, buf8, nullptr, 512, 512);
    k_agg512_f8s<<<N_NODES / 16, 256, 0, stream>>>(buf8, rp, cs, bufA, part);
    k_bn_red1<512, 2000, 100><<<400, 256, 0, stream>>>(part, part2);
    k_bn_red2<512, 100><<<4, 256, 0, stream>>>(part2, sums2);
    k_bn_apply<512><<<N_NODES * 512 / 8 / 256, 256, 0, stream>>>(bufA, sums2, g2, be2);

    // ---- layer 3: GEMM -> agg+stats fused -> reduce (BN3 applied inside pool) ----
    k_gemm_mfma<false, false, true, false><<<dim3(250, 2), 256, 0, stream>>>(bufA, w3b, b3, rp, buf8, nullptr, 512, 256);
    k_agg256_f8s<<<N_NODES / 16, 256, 0, stream>>>(buf8, rp, cs, bufB, part);
    k_bn_red1<256, 2000, 100><<<200, 256, 0, stream>>>(part, part2);
    k_bn_red2<256, 100><<<2, 256, 0, stream>>>(part2, sums3);

    // ---- pool (fused BN3+leaky) + head ----
    k_pool_bn<<<N_NODES / 16, 256, 0, stream>>>(bufB, sums3, g3, be3, ppool);
    k_head<<<16, 256, 0, stream>>>(ppool, Wp, bp, out);
}

// Round 17
// 323.451 us; speedup vs baseline: 1.0323x; 1.0323x over previous
//
#include <hip/hip_runtime.h>

#define N_NODES 32000
typedef unsigned short u16;
typedef unsigned int u32;
typedef unsigned char u8;
typedef __attribute__((ext_vector_type(8))) short bf16x8;
typedef __attribute__((ext_vector_type(4))) float f32x4;
typedef __attribute__((ext_vector_type(2))) float f32x2;

__device__ __forceinline__ float leakyf(float v) { return v >= 0.f ? v : 0.1f * v; }
__device__ __forceinline__ u16 f2bf(float f) {
    u32 u = __float_as_uint(f);
    return (u16)((u + 0x7FFFu + ((u >> 16) & 1u)) >> 16);
}
__device__ __forceinline__ float bf_lo(u32 u) { return __uint_as_float(u << 16); }
__device__ __forceinline__ float bf_hi(u32 u) { return __uint_as_float(u & 0xFFFF0000u); }
__device__ __forceinline__ u32 pack2(float a, float b) { return (u32)f2bf(a) | ((u32)f2bf(b) << 16); }

__device__ __forceinline__ void dec4(float* acc, u32 w) {
    f32x2 lo = __builtin_amdgcn_cvt_pk_f32_fp8(w, false);
    f32x2 hi = __builtin_amdgcn_cvt_pk_f32_fp8(w, true);
    acc[0] += lo[0]; acc[1] += lo[1]; acc[2] += hi[0]; acc[3] += hi[1];
}
__device__ __forceinline__ void dec16(float* acc, uint4 v) {
    dec4(acc + 0, v.x); dec4(acc + 4, v.y); dec4(acc + 8, v.z); dec4(acc + 12, v.w);
}
__device__ __forceinline__ u8 f2fp8(float v) {
    return (u8)__builtin_amdgcn_cvt_pk_fp8_f32(v, v, 0, false);
}

__device__ __forceinline__ void gload16(const u16* g, u16* l) {
    __builtin_amdgcn_global_load_lds((const __attribute__((address_space(1))) void*)g,
                                     (__attribute__((address_space(3))) void*)l, 16, 0, 0);
}

// ---------------- fused prep: edge-count | x->fp8 | weights->bf16 ----------------
__global__ __launch_bounds__(256) void k_prep(const int* __restrict__ dst, int* __restrict__ cnt, int E,
                                              const float* __restrict__ x, u32* __restrict__ x8,
                                              const float* __restrict__ W1, const float* __restrict__ W2,
                                              const float* __restrict__ W3, u16* __restrict__ o1,
                                              u16* __restrict__ o2, u16* __restrict__ o3)
{
    const int b = blockIdx.x, t = threadIdx.x;
    if (b < 2000) {
        int e = b * 256 + t;
        if (e < E) atomicAdd(&cnt[dst[e]], 1);
    } else if (b < 10000) {
        int i = (b - 2000) * 256 + t;
        float4 v = ((const float4*)x)[i];
        int p = __builtin_amdgcn_cvt_pk_fp8_f32(v.x, v.y, 0, false);
        p = __builtin_amdgcn_cvt_pk_fp8_f32(v.z, v.w, p, true);
        x8[i] = (u32)p;
    } else {
        int bb = b - 10000;
        const float* in; u16* out; int i;
        if (bb < 128)      { in = W1; out = o1; i = bb * 256 + t; }
        else if (bb < 384) { in = W2; out = o2; i = (bb - 128) * 256 + t; }
        else               { in = W3; out = o3; i = (bb - 384) * 256 + t; }
        float4 v = ((const float4*)in)[i];
        ushort4 o;
        o.x = f2bf(v.x); o.y = f2bf(v.y); o.z = f2bf(v.z); o.w = f2bf(v.w);
        ((ushort4*)out)[i] = o;
    }
}

// ---------------- CSR scan ----------------
__global__ __launch_bounds__(256) void k_scan_blk(const int* __restrict__ cnt, int* __restrict__ rp,
                                                  int* __restrict__ bsum)
{
    __shared__ int sh[256];
    const int b = blockIdx.x, t = threadIdx.x;
    int v = cnt[b * 256 + t];
    sh[t] = v;
    __syncthreads();
    for (int off = 1; off < 256; off <<= 1) {
        int u = (t >= off) ? sh[t - off] : 0;
        __syncthreads();
        sh[t] += u;
        __syncthreads();
    }
    rp[b * 256 + t] = sh[t] - v;
    if (t == 255) bsum[b] = sh[255];
}

__global__ __launch_bounds__(256) void k_scan_add(int* __restrict__ rp, const int* __restrict__ bsum,
                                                  int nb, int n, int E)
{
    __shared__ int sh[256];
    const int b = blockIdx.x, t = threadIdx.x;
    int v = (t < b && t < nb) ? bsum[t] : 0;
    sh[t] = v;
    __syncthreads();
    for (int off = 128; off > 0; off >>= 1) {
        if (t < off) sh[t] += sh[t + off];
        __syncthreads();
    }
    int i = b * 256 + t;
    rp[i] += sh[0];
    if (i == 0) rp[n] = E;
}

__global__ __launch_bounds__(256) void k_place(const int* __restrict__ src, const int* __restrict__ dst,
                                               const int* __restrict__ rp, int* __restrict__ cur,
                                               int* __restrict__ cs, int E)
{
    int e = blockIdx.x * 256 + threadIdx.x;
    if (e < E) {
        int d = dst[e];
        int p = rp[d] + atomicAdd(&cur[d], 1);
        cs[p] = src[e];
    }
}

// ---------------- bf16 MFMA GEMM, dbuf + counted vmcnt; optional fused column stats ----------------
template <bool RELU, bool DEGB, bool F8OUT, bool STATS>
__global__ __launch_bounds__(256) void k_gemm_mfma(const u16* __restrict__ A, const u16* __restrict__ W,
                                                   const float* __restrict__ bias, const int* __restrict__ rp,
                                                   void* __restrict__ Cv, float* __restrict__ partial,
                                                   int K, int OD)
{
    __shared__ u16 As[2][128 * 32];
    __shared__ u16 Bs[2][128 * 32];
    const int t = threadIdx.x;
    const int lane = t & 63;
    const int w = t >> 6;
    const int wr = w >> 1, wc = w & 1;
    const int bm = blockIdx.x * 128;
    const int bn = blockIdx.y * 128;

    const int c0 = w * 64 + lane;
    const int r0 = c0 >> 2, kc0 = (c0 & 3) * 8;
    const int c1 = c0 + 256;
    const int r1 = c1 >> 2, kc1 = (c1 & 3) * 8;
    const u16* gA0 = A + (size_t)(bm + r0) * K + kc0;
    const u16* gA1 = A + (size_t)(bm + r1) * K + kc1;
    const u16* gB0 = W + (size_t)(bn + r0) * K + kc0;
    const u16* gB1 = W + (size_t)(bn + r1) * K + kc1;

    f32x4 acc[4][4];
#pragma unroll
    for (int i = 0; i < 4; ++i)
#pragma unroll
        for (int j = 0; j < 4; ++j)
            acc[i][j] = (f32x4){0.f, 0.f, 0.f, 0.f};

    const int fr = lane & 15;
    const int ko = (lane >> 4) * 8;

    auto STAGE = [&](int b, int k0) {
        gload16(gA0 + k0, &As[b][0] + w * 512);
        gload16(gA1 + k0, &As[b][0] + 2048 + w * 512);
        gload16(gB0 + k0, &Bs[b][0] + w * 512);
        gload16(gB1 + k0, &Bs[b][0] + 2048 + w * 512);
    };

    STAGE(0, 0);

    int cur = 0;
    for (int k0 = 0; k0 < K; k0 += 32) {
        if (k0 + 32 < K) {
            STAGE(cur ^ 1, k0 + 32);
            asm volatile("s_waitcnt vmcnt(4)" ::: "memory");
        } else {
            asm volatile("s_waitcnt vmcnt(0)" ::: "memory");
        }
        __syncthreads();
        bf16x8 af[4], bfv[4];
#pragma unroll
        for (int i = 0; i < 4; ++i)
            af[i] = *(const bf16x8*)&As[cur][(wr * 64 + i * 16 + fr) * 32 + ko];
#pragma unroll
        for (int j = 0; j < 4; ++j)
            bfv[j] = *(const bf16x8*)&Bs[cur][(wc * 64 + j * 16 + fr) * 32 + ko];
#pragma unroll
        for (int i = 0; i < 4; ++i)
#pragma unroll
            for (int j = 0; j < 4; ++j)
                acc[i][j] = __builtin_amdgcn_mfma_f32_16x16x32_bf16(af[i], bfv[j], acc[i][j], 0, 0, 0);
        __syncthreads();
        cur ^= 1;
    }

    u16* C16 = (u16*)Cv;
    u8*  C8  = (u8*)Cv;
    const int qr = (lane >> 4) * 4;
    float bcol[4];
#pragma unroll
    for (int j = 0; j < 4; ++j) bcol[j] = bias[bn + wc * 64 + j * 16 + fr];
    float s4[4] = {}, q4[4] = {};
#pragma unroll
    for (int i = 0; i < 4; ++i) {
#pragma unroll
        for (int r = 0; r < 4; ++r) {
            int row = bm + wr * 64 + i * 16 + qr + r;
            float bm_ = 1.f;
            if (DEGB) bm_ = (float)(rp[row + 1] - rp[row]) + 1.f;
#pragma unroll
            for (int j = 0; j < 4; ++j) {
                int col = bn + wc * 64 + j * 16 + fr;
                float o = acc[i][j][r] + bm_ * bcol[j];
                if (RELU) o = fmaxf(o, 0.f);
                if (STATS) { s4[j] += o; q4[j] = fmaf(o, o, q4[j]); }
                if (F8OUT) C8[(size_t)row * OD + col] = f2fp8(o);
                else       C16[(size_t)row * OD + col] = f2bf(o);
            }
        }
    }

    if (STATS) {
#pragma unroll
        for (int j = 0; j < 4; ++j) {
            s4[j] += __shfl_xor(s4[j], 16); s4[j] += __shfl_xor(s4[j], 32);
            q4[j] += __shfl_xor(q4[j], 16); q4[j] += __shfl_xor(q4[j], 32);
        }
        __syncthreads();
        float* sred = (float*)&As[0][0];
        if ((lane >> 4) == 0) {
#pragma unroll
            for (int j = 0; j < 4; ++j) {
                sred[((w * 4 + j) * 16 + fr) * 2 + 0] = s4[j];
                sred[((w * 4 + j) * 16 + fr) * 2 + 1] = q4[j];
            }
        }
        __syncthreads();
        if (wr == 0 && (lane >> 4) == 0) {
#pragma unroll
            for (int j = 0; j < 4; ++j) {
                int i0 = ((w * 4 + j) * 16 + fr) * 2;
                int i1 = (((w + 2) * 4 + j) * 16 + fr) * 2;
                float ss = sred[i0] + sred[i1];
                float qq = sred[i0 + 1] + sred[i1 + 1];
                int col = bn + wc * 64 + j * 16 + fr;
                partial[(size_t)blockIdx.x * 1024 + col]       = ss;
                partial[(size_t)blockIdx.x * 1024 + 512 + col] = qq;
            }
        }
    }
}

// ---------------- fp8 gather+self(+relu), D=256 ----------------
template <bool RELU>
__global__ __launch_bounds__(256) void k_agg256_f8(const u8* __restrict__ h8, const int* __restrict__ rp,
                                                   const int* __restrict__ cs, u16* __restrict__ out)
{
    const int lane = threadIdx.x & 63;
    const int n = blockIdx.x * 4 + (threadIdx.x >> 6);
    const int g = lane >> 4;
    const int c = lane & 15;
    const uint4* hb = (const uint4*)h8 + c;

    float acc[16];
#pragma unroll
    for (int i = 0; i < 16; ++i) acc[i] = 0.f;
    if (g == 0) dec16(acc, hb[(size_t)n * 16]);

    const int beg = rp[n], end = rp[n + 1];
    int e = beg;
    for (; e + 16 <= end; e += 16) {
        uint4 v0 = hb[(size_t)cs[e + g] * 16];
        uint4 v1 = hb[(size_t)cs[e + 4 + g] * 16];
        uint4 v2 = hb[(size_t)cs[e + 8 + g] * 16];
        uint4 v3 = hb[(size_t)cs[e + 12 + g] * 16];
        dec16(acc, v0); dec16(acc, v1); dec16(acc, v2); dec16(acc, v3);
    }
    for (; e + 4 <= end; e += 4) {
        uint4 v = hb[(size_t)cs[e + g] * 16];
        dec16(acc, v);
    }
    if (e + g < end) {
        uint4 v = hb[(size_t)cs[e + g] * 16];
        dec16(acc, v);
    }
#pragma unroll
    for (int i = 0; i < 16; ++i) acc[i] += __shfl_xor(acc[i], 16);
#pragma unroll
    for (int i = 0; i < 16; ++i) acc[i] += __shfl_xor(acc[i], 32);
    if (g == 0) {
        if (RELU) {
#pragma unroll
            for (int i = 0; i < 16; ++i) acc[i] = fmaxf(acc[i], 0.f);
        }
        uint4 o0, o1;
        o0.x = pack2(acc[0], acc[1]);  o0.y = pack2(acc[2], acc[3]);
        o0.z = pack2(acc[4], acc[5]);  o0.w = pack2(acc[6], acc[7]);
        o1.x = pack2(acc[8], acc[9]);  o1.y = pack2(acc[10], acc[11]);
        o1.z = pack2(acc[12], acc[13]); o1.w = pack2(acc[14], acc[15]);
        uint4* op = (uint4*)((u32*)out + (size_t)n * 128 + c * 8);
        op[0] = o0; op[1] = o1;
    }
}

// ---------------- fp8 gather+self(+relu), D=512 ----------------
template <bool RELU>
__global__ __launch_bounds__(256) void k_agg512_f8(const u8* __restrict__ h8, const int* __restrict__ rp,
                                                   const int* __restrict__ cs, u16* __restrict__ out)
{
    const int lane = threadIdx.x & 63;
    const int n = blockIdx.x * 4 + (threadIdx.x >> 6);
    const int g = lane >> 5;
    const int c = lane & 31;
    const uint4* hb = (const uint4*)h8 + c;

    float acc[16];
#pragma unroll
    for (int i = 0; i < 16; ++i) acc[i] = 0.f;
    if (g == 0) dec16(acc, hb[(size_t)n * 32]);

    const int beg = rp[n], end = rp[n + 1];
    int e = beg;
    for (; e + 8 <= end; e += 8) {
        uint4 v0 = hb[(size_t)cs[e + g] * 32];
        uint4 v1 = hb[(size_t)cs[e + 2 + g] * 32];
        uint4 v2 = hb[(size_t)cs[e + 4 + g] * 32];
        uint4 v3 = hb[(size_t)cs[e + 6 + g] * 32];
        dec16(acc, v0); dec16(acc, v1); dec16(acc, v2); dec16(acc, v3);
    }
    for (; e + 2 <= end; e += 2) {
        uint4 v = hb[(size_t)cs[e + g] * 32];
        dec16(acc, v);
    }
    if (e + g < end) {
        uint4 v = hb[(size_t)cs[e + g] * 32];
        dec16(acc, v);
    }
#pragma unroll
    for (int i = 0; i < 16; ++i) acc[i] += __shfl_xor(acc[i], 32);
    if (g == 0) {
        if (RELU) {
#pragma unroll
            for (int i = 0; i < 16; ++i) acc[i] = fmaxf(acc[i], 0.f);
        }
        uint4 o0, o1;
        o0.x = pack2(acc[0], acc[1]);  o0.y = pack2(acc[2], acc[3]);
        o0.z = pack2(acc[4], acc[5]);  o0.w = pack2(acc[6], acc[7]);
        o1.x = pack2(acc[8], acc[9]);  o1.y = pack2(acc[10], acc[11]);
        o1.z = pack2(acc[12], acc[13]); o1.w = pack2(acc[14], acc[15]);
        uint4* op = (uint4*)((u32*)out + (size_t)n * 256 + c * 8);
        op[0] = o0; op[1] = o1;
    }
}

// ---------------- BN stats, stage A (layers 2,3) ----------------
template <int D>
__global__ __launch_bounds__(256) void k_bn_part(const u16* __restrict__ h, float* __restrict__ partial)
{
    constexpr int SLOT = D / 8;
    constexpr int NS = 256 / SLOT;
    constexpr int ROWS = 16;
    const int t = threadIdx.x;
    const int s = t % SLOT, j = t / SLOT;
    const int r0 = blockIdx.x * ROWS;
    float a[8] = {}, q[8] = {};
#pragma unroll
    for (int rr = 0; rr < ROWS / NS; ++rr) {
        int r = j + rr * NS;
        uint4 v = *((const uint4*)(h + (size_t)(r0 + r) * D) + s);
        u32 wv[4] = {v.x, v.y, v.z, v.w};
#pragma unroll
        for (int k = 0; k < 4; ++k) {
            float lo = bf_lo(wv[k]), hi = bf_hi(wv[k]);
            a[2 * k]     += lo; q[2 * k]     = fmaf(lo, lo, q[2 * k]);
            a[2 * k + 1] += hi; q[2 * k + 1] = fmaf(hi, hi, q[2 * k + 1]);
        }
    }
    __shared__ float red[16][256];
#pragma unroll
    for (int i = 0; i < 8; ++i) { red[i][t] = a[i]; red[8 + i][t] = q[i]; }
    __syncthreads();
    if (j == 0) {
        for (int k = 1; k < NS; ++k) {
            int o = k * SLOT + s;
#pragma unroll
            for (int i = 0; i < 8; ++i) { a[i] += red[i][o]; q[i] += red[8 + i][o]; }
        }
        float* pb = partial + (size_t)blockIdx.x * (2 * D);
        float4* p0 = (float4*)(pb + 8 * s);
        p0[0] = make_float4(a[0], a[1], a[2], a[3]);
        p0[1] = make_float4(a[4], a[5], a[6], a[7]);
        float4* p1 = (float4*)(pb + D + 8 * s);
        p1[0] = make_float4(q[0], q[1], q[2], q[3]);
        p1[1] = make_float4(q[4], q[5], q[6], q[7]);
    }
}

// ---------------- BN stats reduce, level 1: P rows -> SEG rows (no atomics) ----------------
template <int D, int P, int SEG>
__global__ __launch_bounds__(256) void k_bn_red1(const float* __restrict__ partial, float* __restrict__ part2)
{
    const int g = blockIdx.x * 256 + threadIdx.x;
    const int col = g & (2 * D - 1);
    const int seg = g / (2 * D);
    constexpr int CHUNK = P / SEG;
    const float* p = partial + (size_t)seg * CHUNK * (2 * D) + col;
    float acc = 0.f;
#pragma unroll
    for (int i = 0; i < CHUNK; ++i) acc += p[(size_t)i * (2 * D)];
    part2[(size_t)seg * (2 * D) + col] = acc;
}

// ---------------- BN stats reduce, level 2: SEG rows -> sums (direct store) ----------------
template <int D, int SEG>
__global__ __launch_bounds__(256) void k_bn_red2(const float* __restrict__ part2, float* __restrict__ sums)
{
    const int col = blockIdx.x * 256 + threadIdx.x;
    float acc = 0.f;
#pragma unroll
    for (int i = 0; i < SEG; ++i) acc += part2[(size_t)i * (2 * D) + col];
    sums[col] = acc;
}

// ---------------- BN apply with inline finalize ----------------
template <int D>
__global__ __launch_bounds__(256) void k_bn_apply(u16* __restrict__ h, const float* __restrict__ sums,
                                                  const float* __restrict__ gam, const float* __restrict__ bet)
{
    int i = blockIdx.x * 256 + threadIdx.x;
    int c = (i * 8) & (D - 1);
    const float invN = 1.f / (float)N_NODES;
    float sc[8], sh[8];
#pragma unroll
    for (int k = 0; k < 8; ++k) {
        float mu  = sums[c + k] * invN;
        float var = sums[D + c + k] * invN - mu * mu;
        float rs  = rsqrtf(var + 1e-5f);
        sc[k] = gam[c + k] * rs;
        sh[k] = bet[c + k] - mu * sc[k];
    }
    uint4 v = ((uint4*)h)[i];
    u32 vv[4] = {v.x, v.y, v.z, v.w};
    u32 r[4];
#pragma unroll
    for (int k = 0; k < 4; ++k) {
        float a = leakyf(fmaf(bf_lo(vv[k]), sc[2 * k], sh[2 * k]));
        float b = leakyf(fmaf(bf_hi(vv[k]), sc[2 * k + 1], sh[2 * k + 1]));
        r[k] = pack2(a, b);
    }
    ((uint4*)h)[i] = make_uint4(r[0], r[1], r[2], r[3]);
}

// ---------------- pool: BN3+leaky fused, NO atomics ----------------
__global__ __launch_bounds__(256) void k_pool_bn(const u16* __restrict__ h, const float* __restrict__ sums,
                                                 const float* __restrict__ gam, const float* __restrict__ bet,
                                                 float* __restrict__ ppool)
{
    const int t = threadIdx.x;
    const int s = t & 31;
    const int j = t >> 5;
    const int r0 = blockIdx.x * 16;
    const float invN = 1.f / (float)N_NODES;
    float sc[8], sh[8];
#pragma unroll
    for (int k = 0; k < 8; ++k) {
        int c = 8 * s + k;
        float mu  = sums[c] * invN;
        float var = sums[256 + c] * invN - mu * mu;
        float rs  = rsqrtf(var + 1e-5f);
        sc[k] = gam[c] * rs;
        sh[k] = bet[c] - mu * sc[k];
    }
    float a[8] = {};
#pragma unroll
    for (int rr = 0; rr < 2; ++rr) {
        int r = r0 + j + rr * 8;
        uint4 v = *((const uint4*)(h + (size_t)r * 256) + s);
        u32 wv[4] = {v.x, v.y, v.z, v.w};
#pragma unroll
        for (int k = 0; k < 4; ++k) {
            a[2 * k]     += leakyf(fmaf(bf_lo(wv[k]), sc[2 * k], sh[2 * k]));
            a[2 * k + 1] += leakyf(fmaf(bf_hi(wv[k]), sc[2 * k + 1], sh[2 * k + 1]));
        }
    }
    __shared__ float red[8][256];
#pragma unroll
    for (int i = 0; i < 8; ++i) red[i][t] = a[i];
    __syncthreads();
    if (j == 0) {
#pragma unroll
        for (int k = 1; k < 8; ++k) {
            int o = k * 32 + s;
#pragma unroll
            for (int i = 0; i < 8; ++i) a[i] += red[i][o];
        }
        float4* pb = (float4*)(ppool + (size_t)blockIdx.x * 256 + 8 * s);
        pb[0] = make_float4(a[0], a[1], a[2], a[3]);
        pb[1] = make_float4(a[4], a[5], a[6], a[7]);
    }
}

// ---------------- head: one block per graph ----------------
__global__ __launch_bounds__(256) void k_head(const float* __restrict__ ppool, const float* __restrict__ Wp,
                                              const float* __restrict__ bp, float* __restrict__ out)
{
    __shared__ float r0s[256], r1s[256];
    const int b = blockIdx.x, t = threadIdx.x;
    const float* p = ppool + (size_t)b * 125 * 256 + t;
    float g = 0.f;
#pragma unroll 5
    for (int i = 0; i < 125; ++i) g += p[(size_t)i * 256];
    g *= (1.f / 2000.f);
    r0s[t] = g * Wp[t];
    r1s[t] = g * Wp[256 + t];
    __syncthreads();
    for (int off = 128; off > 0; off >>= 1) {
        if (t < off) { r0s[t] += r0s[t + off]; r1s[t] += r1s[t + off]; }
        __syncthreads();
    }
    if (t == 0) {
        float o0 = r0s[0] + bp[0];
        float o1 = r1s[0] + bp[1];
        out[b * 2]     = o0;
        out[b * 2 + 1] = o1;
        out[32 + b]    = (o1 > o0) ? 1.f : 0.f;
    }
}

extern "C" void kernel_launch(void* const* d_in, const int* in_sizes, int n_in,
                              void* d_out, int out_size, void* d_ws, size_t ws_size,
                              hipStream_t stream)
{
    const float* x   = (const float*)d_in[0];
    const int*   ei  = (const int*)d_in[1];
    const float* W1  = (const float*)d_in[2];
    const float* b1  = (const float*)d_in[3];
    const float* W2  = (const float*)d_in[4];
    const float* b2  = (const float*)d_in[5];
    const float* W3  = (const float*)d_in[6];
    const float* b3  = (const float*)d_in[7];
    const float* g1  = (const float*)d_in[8];
    const float* be1 = (const float*)d_in[9];
    const float* g2  = (const float*)d_in[10];
    const float* be2 = (const float*)d_in[11];
    const float* g3  = (const float*)d_in[12];
    const float* be3 = (const float*)d_in[13];
    const float* Wp  = (const float*)d_in[14];
    const float* bp  = (const float*)d_in[15];
    float* out = (float*)d_out;

    const int E = in_sizes[1] / 2;
    const int* src = ei;
    const int* dst = ei + E;

    char* ws = (char*)d_ws;
    size_t off = 0;
    auto alloc = [&](size_t bytes) -> void* {
        void* p = ws + off;
        off = (off + bytes + 255) & ~(size_t)255;
        return p;
    };
    u16*   bufA = (u16*)alloc((size_t)N_NODES * 512 * 2);
    u16*   bufB = (u16*)alloc((size_t)N_NODES * 512 * 2);
    u8*    buf8 = (u8*)alloc((size_t)N_NODES * 512);
    u8*    x8   = (u8*)alloc((size_t)N_NODES * 256);
    u16*   w1b  = (u16*)alloc(512 * 256 * 2);
    u16*   w2b  = (u16*)alloc(512 * 512 * 2);
    u16*   w3b  = (u16*)alloc(256 * 512 * 2);
    int*   cs   = (int*)alloc((size_t)E * 4);
    int*   rp   = (int*)alloc((size_t)(N_NODES + 1) * 4);
    int*   cnt  = (int*)alloc((size_t)N_NODES * 4 * 2);
    int*   cur  = cnt + N_NODES;
    const size_t zbytes = (size_t)N_NODES * 8;
    int*   bsum = (int*)alloc(256 * 4);
    float* part = (float*)alloc((size_t)2000 * 1024 * 4);
    float* part2 = (float*)alloc((size_t)100 * 1024 * 4);
    float* sums1 = (float*)alloc(1024 * 4);
    float* sums2 = (float*)alloc(1024 * 4);
    float* sums3 = (float*)alloc(1024 * 4);
    float* ppool = (float*)alloc((size_t)2000 * 256 * 4);

    hipMemsetAsync(cnt, 0, zbytes, stream);

    const int eb = (E + 255) / 256;          // 2000
    const int nb = N_NODES / 256;            // 125

    k_prep<<<eb + 8000 + 512, 256, 0, stream>>>(dst, cnt, E, x, (u32*)x8, W1, W2, W3, w1b, w2b, w3b);
    k_scan_blk<<<nb, 256, 0, stream>>>(cnt, rp, bsum);
    k_scan_add<<<nb, 256, 0, stream>>>(rp, bsum, nb, N_NODES, E);
    k_place<<<eb, 256, 0, stream>>>(src, dst, rp, cur, cs, E);

    const int PB = N_NODES / 16;             // 2000 stage-A blocks

    // ---- layer 1: stats fused in GEMM epilogue (250 partial rows) ----
    k_agg256_f8<false><<<N_NODES / 4, 256, 0, stream>>>(x8, rp, cs, bufA);
    k_gemm_mfma<true, true, false, true><<<dim3(250, 4), 256, 0, stream>>>(bufA, w1b, b1, rp, bufB, part, 256, 512);
    k_bn_red1<512, 250, 25><<<100, 256, 0, stream>>>(part, part2);
    k_bn_red2<512, 25><<<4, 256, 0, stream>>>(part2, sums1);
    k_bn_apply<512><<<N_NODES * 512 / 8 / 256, 256, 0, stream>>>(bufB, sums1, g1, be1);

    // ---- layer 2 ----
    k_gemm_mfma<false, false, true, false><<<dim3(250, 4), 256, 0, stream>>>(bufB, w2b, b2, rp, buf8, nullptr, 512, 512);
    k_agg512_f8<true><<<N_NODES / 4, 256, 0, stream>>>(buf8, rp, cs, bufA);
    k_bn_part<512><<<PB, 256, 0, stream>>>(bufA, part);
    k_bn_red1<512, 2000, 100><<<400, 256, 0, stream>>>(part, part2);
    k_bn_red2<512, 100><<<4, 256, 0, stream>>>(part2, sums2);
    k_bn_apply<512><<<N_NODES * 512 / 8 / 256, 256, 0, stream>>>(bufA, sums2, g2, be2);

    // ---- layer 3: GEMM -> agg -> stats (BN3 applied inside pool) ----
    k_gemm_mfma<false, false, true, false><<<dim3(250, 2), 256, 0, stream>>>(bufA, w3b, b3, rp, buf8, nullptr, 512, 256);
    k_agg256_f8<true><<<N_NODES / 4, 256, 0, stream>>>(buf8, rp, cs, bufB);
    k_bn_part<256><<<PB, 256, 0, stream>>>(bufB, part);
    k_bn_red1<256, 2000, 100><<<200, 256, 0, stream>>>(part, part2);
    k_bn_red2<256, 100><<<2, 256, 0, stream>>>(part2, sums3);

    // ---- pool (fused BN3+leaky, no atomics) + head ----
    k_pool_bn<<<PB, 256, 0, stream>>>(bufB, sums3, g3, be3, ppool);
    k_head<<<16, 256, 0, stream>>>(ppool, Wp, bp, out);
}